// Round 3
// baseline (342.462 us; speedup 1.0000x reference)
//
#include <hip/hip_runtime.h>
#include <math.h>

#define NB 96
#define NB2 (NB * NB)
#define DFEAT 64
#define NCLS 21
#define MARGIN 0.3

typedef int i4 __attribute__((ext_vector_type(4)));  // native vec for nontemporal builtin

// ---------------------------------------------------------------------------
// Kernel A: per (i,j) pair compute
//   mat[i,j]   = -( dot(logits_i, feat2_j) / (max(||logits_i||,eps)*max(||feat2_j||,eps)) )
//   thr[i,j]   = MARGIN + mat[i,j]
//   share[i,j] = (labels_i . labels_j) > 0
// All math in double so we agree with a float64 numpy reference to ~1e-16,
// which makes the (<= 0.3) boolean comparisons effectively exact.
// ---------------------------------------------------------------------------
__global__ void precompute_kernel(const float* __restrict__ logits,
                                  const float* __restrict__ labels,
                                  const float* __restrict__ feat2,
                                  double* __restrict__ mat,
                                  double* __restrict__ thr,
                                  unsigned char* __restrict__ share) {
    int gid = blockIdx.x * blockDim.x + threadIdx.x;
    if (gid >= NB2) return;
    int i = gid / NB;
    int j = gid - i * NB;

    const float* xi = logits + i * DFEAT;
    const float* yj = feat2 + j * DFEAT;
    double nx = 0.0, ny = 0.0, dot = 0.0;
#pragma unroll
    for (int d = 0; d < DFEAT; ++d) {
        double a = (double)xi[d];
        double b = (double)yj[d];
        nx += a * a;
        ny += b * b;
        dot += a * b;
    }
    nx = fmax(sqrt(nx), 1e-12);
    ny = fmax(sqrt(ny), 1e-12);
    double m = -(dot / (nx * ny));
    mat[gid] = m;
    thr[gid] = MARGIN + m;

    const float* li = labels + i * NCLS;
    const float* lj = labels + j * NCLS;
    float ldot = 0.f;
#pragma unroll
    for (int c = 0; c < NCLS; ++c) ldot += li[c] * lj[c];
    share[gid] = (ldot > 0.f) ? 1 : 0;
}

// ---------------------------------------------------------------------------
// Kernel B: one block per (i,j); writes the 96x96 (k,n) int32 0/1 slab.
//   valid[i,j,k,n] = sames[i,j] & sames[i,k] & (j<k) & diffs[i,n]
//                    & (mat[i,n] <= MARGIN + max(mat[i,j], mat[i,k]))
// smat[n] is pre-masked: +inf where diffs[i,n] is false, so the inner loop is
// one double-compare per output element. Stores are nontemporal int4
// (340 MB output stream >> L2).
// ---------------------------------------------------------------------------
__global__ __launch_bounds__(256) void quad_kernel(const double* __restrict__ mat,
                                                   const double* __restrict__ thr,
                                                   const unsigned char* __restrict__ share,
                                                   int* __restrict__ out) {
    const int bid = blockIdx.x;
    const int i = bid / NB;
    const int j = bid - i * NB;
    const int tid = threadIdx.x;

    __shared__ double smat[NB];          // diffs[i,n] ? mat[i,n] : +inf
    __shared__ double sthr[NB];          // MARGIN + mat[i,k]
    __shared__ unsigned char svalid[NB]; // sames[i,k] = share[i,k] && k!=i

    if (tid < NB) {
        unsigned char s = share[i * NB + tid];
        double m = mat[i * NB + tid];
        smat[tid] = s ? 1e300 : m; // diffs = !share (diagonal NOT excluded, per ref)
        sthr[tid] = thr[i * NB + tid];
        svalid[tid] = (s && tid != i) ? 1 : 0;
    }
    __syncthreads();

    const bool sames_ij = (svalid[j] != 0);
    const double thr_ij = sthr[j];
    i4* outp = (i4*)(out + (size_t)bid * (size_t)(NB * NB));

    // 96 k-rows * 24 int4-chunks per row = 2304 chunks; 256 threads -> 9 each.
#pragma unroll
    for (int r = 0; r < 9; ++r) {
        int c = r * 256 + tid;
        int k = c / 24;
        int q = c - k * 24;
        i4 v = (i4)(0);
        if (sames_ij && svalid[k] && (j < k)) {
            double t = fmax(thr_ij, sthr[k]);
            int n0 = q * 4;
            v.x = (smat[n0 + 0] <= t) ? 1 : 0;
            v.y = (smat[n0 + 1] <= t) ? 1 : 0;
            v.z = (smat[n0 + 2] <= t) ? 1 : 0;
            v.w = (smat[n0 + 3] <= t) ? 1 : 0;
        }
        __builtin_nontemporal_store(v, &outp[c]);
    }
}

extern "C" void kernel_launch(void* const* d_in, const int* in_sizes, int n_in,
                              void* d_out, int out_size, void* d_ws, size_t ws_size,
                              hipStream_t stream) {
    const float* logits = (const float*)d_in[0]; // [96,64]
    const float* labels = (const float*)d_in[1]; // [96,21]
    const float* feat2  = (const float*)d_in[2]; // [96,64]
    int* out = (int*)d_out;                      // [96,96,96,96] as 0/1 int32

    double* mat = (double*)d_ws;               // 9216 doubles
    double* thr = mat + NB2;                   // 9216 doubles
    unsigned char* share = (unsigned char*)(thr + NB2); // 9216 bytes

    precompute_kernel<<<(NB2 + 255) / 256, 256, 0, stream>>>(logits, labels, feat2,
                                                             mat, thr, share);
    quad_kernel<<<NB2, 256, 0, stream>>>(mat, thr, share, out);
}